// Round 9
// baseline (166.114 us; speedup 1.0000x reference)
//
#include <hip/hip_runtime.h>

// CausalWanSelfAttention: DIM=1024, 64 heads of head-dim 1, N=2048.
// out[i,c] = sum_h w_out[c,h] * softmax_j<=i( q[i,h]*k[j,h]/8 ) . v[j,h]
//
// 4 kernels:
//   prep:     wT[k][f] (k-cols pre-scaled by log2e/8), wOutT[h][c], zero qsv
//   qkv_gemm: split-K=8 tiled GEMM, atomicAdd epilogue -> qsv = q|sk|v [3][64][2048]
//   attn:     block=(h, pair{p,31-p}) perfectly balanced, LDS-staged rows,
//             exp2 hot loop -> pn/pd[4][64][2048] (4 j-slices)
//   proj:     sums 4 slices + divide in LDS, then out = a . wOutT

#if __has_builtin(__builtin_amdgcn_exp2f)
#define EXP2F(x) __builtin_amdgcn_exp2f(x)
#else
#define EXP2F(x) exp2f(x)
#endif

#define LOG2E_DIV8 0.18033688011112042f  // log2(e)/8

// grid 1408: [0,768) transpose+scale w_qkv, [768,1024) transpose w_out, [1024,1408) zero qsv
__global__ __launch_bounds__(256) void prep_kernel(const float* __restrict__ wqkv,
                                                   const float* __restrict__ wout,
                                                   float* __restrict__ wT,
                                                   float* __restrict__ wOutT,
                                                   float* __restrict__ qsv) {
    const int b = blockIdx.x;
    if (b < 768) {
        int idx = b * 256 + threadIdx.x;        // 196608 = 192*1024
        int f = idx >> 10, k = idx & 1023;      // wqkv[f][k]
        float val = wqkv[idx];
        if (f >= 64 && f < 128) val *= LOG2E_DIV8;   // fold attn scale into k-features
        wT[k * 192 + f] = val;
    } else if (b < 1024) {
        int idx = (b - 768) * 256 + threadIdx.x; // 65536 = 1024*64, wout[c][h]
        int cc = idx >> 6, hh = idx & 63;
        wOutT[hh * 1024 + cc] = wout[idx];
    } else {
        int idx = (b - 1024) * 256 + threadIdx.x; // 98304 float4 = 393216 floats
        float4 z = make_float4(0.f, 0.f, 0.f, 0.f);
        ((float4*)qsv)[idx] = z;
    }
}

// C[2048][192] = x[2048][1024] * wT[1024][192], split-K=8 (K=128 per block).
// grid 768 = 32 mtiles * 3 ntiles * 8 ksplit; block 256; micro-tile 4x4.
// Epilogue: atomicAdd into qsv (q|sk|v head-major).
__global__ __launch_bounds__(256) void qkv_gemm(const float* __restrict__ x,
                                                const float* __restrict__ wT,
                                                float* __restrict__ qsv) {
    __shared__ float xsT[32][64];   // [k][row]
    __shared__ float wsld[32][64];  // [k][f]
    const int t = threadIdx.x;
    const int b = blockIdx.x;
    const int ks = b & 7;
    const int nt = (b >> 3) % 3;
    const int mt = b / 24;
    const int i0 = mt * 64;
    const int cb = nt * 64;
    const int k0 = ks * 128;

    const int rf = t & 63;    // staging row (x) / f (w)
    const int kq = t >> 6;    // 0..3
    const int tx = t & 15;
    const int ty = t >> 4;

    const float* xp = x + (size_t)(i0 + rf) * 1024 + k0 + kq * 8;
    const float* wp = wT + (size_t)(k0 + kq * 8) * 192 + cb + rf;

    float4 xa = *(const float4*)(xp);
    float4 xb = *(const float4*)(xp + 4);
    float wr[8];
#pragma unroll
    for (int j = 0; j < 8; ++j) wr[j] = wp[(size_t)j * 192];

    float acc[4][4] = {};

    for (int s = 0; s < 4; ++s) {
        __syncthreads();
        {
            const int kb = kq * 8;
            xsT[kb + 0][rf] = xa.x; xsT[kb + 1][rf] = xa.y;
            xsT[kb + 2][rf] = xa.z; xsT[kb + 3][rf] = xa.w;
            xsT[kb + 4][rf] = xb.x; xsT[kb + 5][rf] = xb.y;
            xsT[kb + 6][rf] = xb.z; xsT[kb + 7][rf] = xb.w;
#pragma unroll
            for (int j = 0; j < 8; ++j) wsld[kb + j][rf] = wr[j];
        }
        __syncthreads();
        if (s < 3) {
            const float* xp2 = xp + (s + 1) * 32;
            xa = *(const float4*)(xp2);
            xb = *(const float4*)(xp2 + 4);
            const float* wp2 = wp + (size_t)(s + 1) * 32 * 192;
#pragma unroll
            for (int j = 0; j < 8; ++j) wr[j] = wp2[(size_t)j * 192];
        }
#pragma unroll
        for (int k = 0; k < 32; ++k) {
            float4 a4 = *(const float4*)&xsT[k][ty * 4];
            float4 b4 = *(const float4*)&wsld[k][tx * 4];
            acc[0][0] = fmaf(a4.x, b4.x, acc[0][0]);
            acc[0][1] = fmaf(a4.x, b4.y, acc[0][1]);
            acc[0][2] = fmaf(a4.x, b4.z, acc[0][2]);
            acc[0][3] = fmaf(a4.x, b4.w, acc[0][3]);
            acc[1][0] = fmaf(a4.y, b4.x, acc[1][0]);
            acc[1][1] = fmaf(a4.y, b4.y, acc[1][1]);
            acc[1][2] = fmaf(a4.y, b4.z, acc[1][2]);
            acc[1][3] = fmaf(a4.y, b4.w, acc[1][3]);
            acc[2][0] = fmaf(a4.z, b4.x, acc[2][0]);
            acc[2][1] = fmaf(a4.z, b4.y, acc[2][1]);
            acc[2][2] = fmaf(a4.z, b4.z, acc[2][2]);
            acc[2][3] = fmaf(a4.z, b4.w, acc[2][3]);
            acc[3][0] = fmaf(a4.w, b4.x, acc[3][0]);
            acc[3][1] = fmaf(a4.w, b4.y, acc[3][1]);
            acc[3][2] = fmaf(a4.w, b4.z, acc[3][2]);
            acc[3][3] = fmaf(a4.w, b4.w, acc[3][3]);
        }
    }

#pragma unroll
    for (int cc = 0; cc < 4; ++cc) {
        const int f = cb + tx * 4 + cc;
        const int which = f >> 6;          // 0=q 1=sk 2=v
        const int h = f & 63;
        float* dst = qsv + (size_t)which * 131072 + (size_t)h * 2048 + i0 + ty * 4;
#pragma unroll
        for (int rr = 0; rr < 4; ++rr) atomicAdd(dst + rr, acc[rr][cc]);
    }
}

// attn: block = (h, p), p=0..15 handles row-blocks rb1=p and rb2=31-p.
// Total j-work per block = (p+1)*64 + (32-p)*64 = 2112 (uniform!). 4 waves
// each take a 528-elem (16-aligned) slice of the concatenated [A|B] range.
// Scores bounded (|score| <~ 1.3 nats) -> no max subtraction.
__global__ __launch_bounds__(256) void attn_kernel(const float* __restrict__ qsv,
                                                   float* __restrict__ pn,
                                                   float* __restrict__ pd) {
    __shared__ float ssk[2048];
    __shared__ float svv[2048];
    const int t = threadIdx.x;
    const int h = blockIdx.x & 63;
    const int p = blockIdx.x >> 6;          // 0..15
    const int lane = t & 63;
    const int c = t >> 6;                   // j-slice 0..3

    const int Alen = (p + 1) * 64;          // rows rb1=p need j in [0, Alen)
    const int L    = (32 - p) * 64;         // rows rb2=31-p need j in [0, L); Alen <= L
    const float* skp = qsv + 131072 + (size_t)h * 2048;
    const float* vp  = qsv + 262144 + (size_t)h * 2048;

    for (int idx = t * 4; idx < L; idx += 1024) {
        *(float4*)&ssk[idx] = *(const float4*)(skp + idx);
        *(float4*)&svv[idx] = *(const float4*)(vp + idx);
    }
    __syncthreads();

    const int i1 = Alen - 64 + lane;        // row in block rb1
    const int i2 = L - 64 + lane;           // row in block rb2
    const float qv1 = qsv[(size_t)h * 2048 + i1];
    const float qv2 = qsv[(size_t)h * 2048 + i2];

    float dA[4] = {0.f, 0.f, 0.f, 0.f}, nA[4] = {0.f, 0.f, 0.f, 0.f};
    float dB[4] = {0.f, 0.f, 0.f, 0.f}, nB[4] = {0.f, 0.f, 0.f, 0.f};

    const int gs = c * 528, ge = gs + 528;

    // ---- part A: rows rb1=p, j-range [gs, min(ge,Alen)) ----
    if (gs < Alen) {
        const int a1 = (ge < Alen) ? ge : Alen;
        const int d1 = Alen - 64;           // diagonal block start
        const int be = (a1 < d1) ? a1 : d1;
        for (int j = gs; j < be; j += 16) {
#pragma unroll
            for (int u = 0; u < 4; ++u) {
                float4 s = *(const float4*)&ssk[j + 4 * u];
                float4 v = *(const float4*)&svv[j + 4 * u];
                float e0 = EXP2F(qv1 * s.x), e1 = EXP2F(qv1 * s.y);
                float e2 = EXP2F(qv1 * s.z), e3 = EXP2F(qv1 * s.w);
                dA[0] += e0; nA[0] = fmaf(e0, v.x, nA[0]);
                dA[1] += e1; nA[1] = fmaf(e1, v.y, nA[1]);
                dA[2] += e2; nA[2] = fmaf(e2, v.z, nA[2]);
                dA[3] += e3; nA[3] = fmaf(e3, v.w, nA[3]);
            }
        }
        const int ms = (gs > d1) ? gs : d1;
        for (int j = ms; j < a1; j += 16) {
#pragma unroll
            for (int u = 0; u < 4; ++u) {
                float4 s = *(const float4*)&ssk[j + 4 * u];
                float4 v = *(const float4*)&svv[j + 4 * u];
                const int jb = j + 4 * u;
                float e0 = (jb     <= i1) ? EXP2F(qv1 * s.x) : 0.f;
                float e1 = (jb + 1 <= i1) ? EXP2F(qv1 * s.y) : 0.f;
                float e2 = (jb + 2 <= i1) ? EXP2F(qv1 * s.z) : 0.f;
                float e3 = (jb + 3 <= i1) ? EXP2F(qv1 * s.w) : 0.f;
                dA[0] += e0; nA[0] = fmaf(e0, v.x, nA[0]);
                dA[1] += e1; nA[1] = fmaf(e1, v.y, nA[1]);
                dA[2] += e2; nA[2] = fmaf(e2, v.z, nA[2]);
                dA[3] += e3; nA[3] = fmaf(e3, v.w, nA[3]);
            }
        }
    }

    // ---- part B: rows rb2=31-p, j-range [max(gs,Alen)-Alen, ge-Alen) ----
    if (ge > Alen) {
        const int b0 = ((gs > Alen) ? gs : Alen) - Alen;
        const int b1 = ge - Alen;
        const int d2 = L - 64;
        const int be = (b1 < d2) ? b1 : d2;
        for (int j = b0; j < be; j += 16) {
#pragma unroll
            for (int u = 0; u < 4; ++u) {
                float4 s = *(const float4*)&ssk[j + 4 * u];
                float4 v = *(const float4*)&svv[j + 4 * u];
                float e0 = EXP2F(qv2 * s.x), e1 = EXP2F(qv2 * s.y);
                float e2 = EXP2F(qv2 * s.z), e3 = EXP2F(qv2 * s.w);
                dB[0] += e0; nB[0] = fmaf(e0, v.x, nB[0]);
                dB[1] += e1; nB[1] = fmaf(e1, v.y, nB[1]);
                dB[2] += e2; nB[2] = fmaf(e2, v.z, nB[2]);
                dB[3] += e3; nB[3] = fmaf(e3, v.w, nB[3]);
            }
        }
        const int ms = (b0 > d2) ? b0 : d2;
        for (int j = ms; j < b1; j += 16) {
#pragma unroll
            for (int u = 0; u < 4; ++u) {
                float4 s = *(const float4*)&ssk[j + 4 * u];
                float4 v = *(const float4*)&svv[j + 4 * u];
                const int jb = j + 4 * u;
                float e0 = (jb     <= i2) ? EXP2F(qv2 * s.x) : 0.f;
                float e1 = (jb + 1 <= i2) ? EXP2F(qv2 * s.y) : 0.f;
                float e2 = (jb + 2 <= i2) ? EXP2F(qv2 * s.z) : 0.f;
                float e3 = (jb + 3 <= i2) ? EXP2F(qv2 * s.w) : 0.f;
                dB[0] += e0; nB[0] = fmaf(e0, v.x, nB[0]);
                dB[1] += e1; nB[1] = fmaf(e1, v.y, nB[1]);
                dB[2] += e2; nB[2] = fmaf(e2, v.z, nB[2]);
                dB[3] += e3; nB[3] = fmaf(e3, v.w, nB[3]);
            }
        }
    }

    const size_t base = ((size_t)c * 64 + h) * 2048;
    pn[base + i1] = (nA[0] + nA[1]) + (nA[2] + nA[3]);
    pd[base + i1] = (dA[0] + dA[1]) + (dA[2] + dA[3]);
    pn[base + i2] = (nB[0] + nB[1]) + (nB[2] + nB[3]);
    pd[base + i2] = (dB[0] + dB[1]) + (dB[2] + dB[3]);
}

// proj: out[i][c] = sum_h a[i][h] * wOutT[h][c], a = (sum pn slots)/(sum pd slots).
// grid 2048 = 256 i-tiles(8 rows) x 8 c-tiles(128 cols); block 256.
__global__ __launch_bounds__(256) void proj_kernel(const float* __restrict__ pn,
                                                   const float* __restrict__ pd,
                                                   const float* __restrict__ wOutT,
                                                   float* __restrict__ out) {
    __shared__ float ast[64][8];
    const int t = threadIdx.x;
    const int i0 = (blockIdx.x >> 3) * 8;
    const int c0 = (blockIdx.x & 7) * 128;

    for (int s = t; s < 512; s += 256) {
        const int hh = s >> 3, ii = s & 7;
        const size_t o = (size_t)hh * 2048 + i0 + ii;
        float n = (pn[o] + pn[131072 + o]) + (pn[262144 + o] + pn[393216 + o]);
        float d = (pd[o] + pd[131072 + o]) + (pd[262144 + o] + pd[393216 + o]);
        ast[hh][ii] = n / d;
    }
    __syncthreads();

    const int rg = t >> 5;      // row 0..7
    const int cg = t & 31;      // col-quad 0..31
    const float* wp = wOutT + c0 + cg * 4;
    float a0 = 0.f, a1 = 0.f, a2 = 0.f, a3 = 0.f;
#pragma unroll 8
    for (int hc = 0; hc < 64; ++hc) {
        float4 w4 = *(const float4*)(wp + (size_t)hc * 1024);
        float a = ast[hc][rg];
        a0 = fmaf(a, w4.x, a0);
        a1 = fmaf(a, w4.y, a1);
        a2 = fmaf(a, w4.z, a2);
        a3 = fmaf(a, w4.w, a3);
    }
    *(float4*)(out + (size_t)(i0 + rg) * 1024 + c0 + cg * 4) = make_float4(a0, a1, a2, a3);
}

extern "C" void kernel_launch(void* const* d_in, const int* in_sizes, int n_in,
                              void* d_out, int out_size, void* d_ws, size_t ws_size,
                              hipStream_t stream) {
    const float* x     = (const float*)d_in[0];   // [1,2048,1024]
    const float* w_qkv = (const float*)d_in[1];   // [192,1024]
    const float* w_out = (const float*)d_in[2];   // [1024,64]
    float* out = (float*)d_out;                   // [1,2048,1024]

    float* ws    = (float*)d_ws;
    float* wT    = ws;                 // 196608
    float* wOutT = wT + 196608;        // 65536
    float* qsv   = wOutT + 65536;      // 3*64*2048 = 393216  (q | sk | v)
    float* pn    = qsv + 393216;       // 4*64*2048 = 524288
    float* pd    = pn + 524288;        // 524288

    prep_kernel<<<dim3(1408), dim3(256), 0, stream>>>(w_qkv, w_out, wT, wOutT, qsv);
    qkv_gemm<<<dim3(768), dim3(256), 0, stream>>>(x, wT, qsv);
    attn_kernel<<<dim3(1024), dim3(256), 0, stream>>>(qsv, pn, pd);
    proj_kernel<<<dim3(2048), dim3(256), 0, stream>>>(pn, pd, wOutT, out);
}

// Round 10
// 127.044 us; speedup vs baseline: 1.3075x; 1.3075x over previous
//
#include <hip/hip_runtime.h>

// CausalWanSelfAttention: DIM=1024, 64 heads of head-dim 1, N=2048.
// out[i,c] = sum_h w_out[c,h] * softmax_j<=i( q[i,h]*k[j,h]/8 ) . v[j,h]
//
// 5 kernels (NO atomics — R9 showed atomicAdd epilogue = 48MB write amp + 59us):
//   prep:       wT[k][f] (k-cols pre-scaled by log2e/8), wOutT[h][c]
//   qkv_gemm:   split-K=8 tiled GEMM -> pq[8][192][2048] f-major partials (coalesced)
//   qkv_reduce: sum 8 partials -> qsv = q|sk|v [3][64][2048]
//   attn:       block=(h, pair{p,31-p}) balanced, LDS-staged, exp2 -> pn/pd[4][64][2048]
//   proj:       sums 4 slices + divide in LDS, then out = a . wOutT
// ws aliasing: pq shares memory with pn/pd (pq dead after qkv_reduce).

#if __has_builtin(__builtin_amdgcn_exp2f)
#define EXP2F(x) __builtin_amdgcn_exp2f(x)
#else
#define EXP2F(x) exp2f(x)
#endif

#define LOG2E_DIV8 0.18033688011112042f  // log2(e)/8

// grid 1024: [0,768) transpose+scale w_qkv, [768,1024) transpose w_out
__global__ __launch_bounds__(256) void prep_kernel(const float* __restrict__ wqkv,
                                                   const float* __restrict__ wout,
                                                   float* __restrict__ wT,
                                                   float* __restrict__ wOutT) {
    const int b = blockIdx.x;
    if (b < 768) {
        int idx = b * 256 + threadIdx.x;        // 196608 = 192*1024
        int f = idx >> 10, k = idx & 1023;      // wqkv[f][k]
        float val = wqkv[idx];
        if (f >= 64 && f < 128) val *= LOG2E_DIV8;   // fold attn scale into k-features
        wT[k * 192 + f] = val;
    } else {
        int idx = (b - 768) * 256 + threadIdx.x; // 65536 = 1024*64, wout[c][h]
        int cc = idx >> 6, hh = idx & 63;
        wOutT[hh * 1024 + cc] = wout[idx];
    }
}

// C[2048][192] = x[2048][1024] * wT[1024][192], split-K=8 (K=128 per block).
// grid 768 = 32 mtiles * 3 ntiles * 8 ksplit; block 256; micro-tile 4x4.
// Epilogue: coalesced f-major partial writes pq[ks][f][i].
__global__ __launch_bounds__(256) void qkv_gemm(const float* __restrict__ x,
                                                const float* __restrict__ wT,
                                                float* __restrict__ pq) {
    __shared__ float xsT[32][64];   // [k][row]
    __shared__ float wsld[32][64];  // [k][f]
    const int t = threadIdx.x;
    const int b = blockIdx.x;
    const int ks = b & 7;
    const int nt = (b >> 3) % 3;
    const int mt = b / 24;
    const int i0 = mt * 64;
    const int cb = nt * 64;
    const int k0 = ks * 128;

    const int rf = t & 63;    // staging row (x) / f (w)
    const int kq = t >> 6;    // 0..3
    const int tx = t & 15;
    const int ty = t >> 4;

    const float* xp = x + (size_t)(i0 + rf) * 1024 + k0 + kq * 8;
    const float* wp = wT + (size_t)(k0 + kq * 8) * 192 + cb + rf;

    float4 xa = *(const float4*)(xp);
    float4 xb = *(const float4*)(xp + 4);
    float wr[8];
#pragma unroll
    for (int j = 0; j < 8; ++j) wr[j] = wp[(size_t)j * 192];

    float acc[4][4] = {};

    for (int s = 0; s < 4; ++s) {
        __syncthreads();
        {
            const int kb = kq * 8;
            xsT[kb + 0][rf] = xa.x; xsT[kb + 1][rf] = xa.y;
            xsT[kb + 2][rf] = xa.z; xsT[kb + 3][rf] = xa.w;
            xsT[kb + 4][rf] = xb.x; xsT[kb + 5][rf] = xb.y;
            xsT[kb + 6][rf] = xb.z; xsT[kb + 7][rf] = xb.w;
#pragma unroll
            for (int j = 0; j < 8; ++j) wsld[kb + j][rf] = wr[j];
        }
        __syncthreads();
        if (s < 3) {
            const float* xp2 = xp + (s + 1) * 32;
            xa = *(const float4*)(xp2);
            xb = *(const float4*)(xp2 + 4);
            const float* wp2 = wp + (size_t)(s + 1) * 32 * 192;
#pragma unroll
            for (int j = 0; j < 8; ++j) wr[j] = wp2[(size_t)j * 192];
        }
#pragma unroll
        for (int k = 0; k < 32; ++k) {
            float4 a4 = *(const float4*)&xsT[k][ty * 4];
            float4 b4 = *(const float4*)&wsld[k][tx * 4];
            acc[0][0] = fmaf(a4.x, b4.x, acc[0][0]);
            acc[0][1] = fmaf(a4.x, b4.y, acc[0][1]);
            acc[0][2] = fmaf(a4.x, b4.z, acc[0][2]);
            acc[0][3] = fmaf(a4.x, b4.w, acc[0][3]);
            acc[1][0] = fmaf(a4.y, b4.x, acc[1][0]);
            acc[1][1] = fmaf(a4.y, b4.y, acc[1][1]);
            acc[1][2] = fmaf(a4.y, b4.z, acc[1][2]);
            acc[1][3] = fmaf(a4.y, b4.w, acc[1][3]);
            acc[2][0] = fmaf(a4.z, b4.x, acc[2][0]);
            acc[2][1] = fmaf(a4.z, b4.y, acc[2][1]);
            acc[2][2] = fmaf(a4.z, b4.z, acc[2][2]);
            acc[2][3] = fmaf(a4.z, b4.w, acc[2][3]);
            acc[3][0] = fmaf(a4.w, b4.x, acc[3][0]);
            acc[3][1] = fmaf(a4.w, b4.y, acc[3][1]);
            acc[3][2] = fmaf(a4.w, b4.z, acc[3][2]);
            acc[3][3] = fmaf(a4.w, b4.w, acc[3][3]);
        }
    }

    // coalesced partial write, f-major: pq[ks][cb+tx*4+cc][i0+ty*4 .. +3]
    float* pbase = pq + (size_t)ks * 192 * 2048 + (size_t)cb * 2048 + i0;
#pragma unroll
    for (int cc = 0; cc < 4; ++cc) {
        float4 o = make_float4(acc[0][cc], acc[1][cc], acc[2][cc], acc[3][cc]);
        *(float4*)(pbase + (size_t)(tx * 4 + cc) * 2048 + ty * 4) = o;
    }
}

// sum 8 partials -> qsv (q|sk|v head-major). Scale already folded into wT.
__global__ __launch_bounds__(256) void qkv_reduce(const float* __restrict__ pq,
                                                  float* __restrict__ qsv) {
    const int idx = blockIdx.x * 256 + threadIdx.x;   // 98304 threads
    const int f = idx >> 9;                           // 0..191
    const int i = (idx & 511) * 4;
    const size_t S = (size_t)192 * 2048;
    const size_t o = (size_t)f * 2048 + i;
    float4 a0 = *(const float4*)(pq + o);
    float4 a1 = *(const float4*)(pq + S + o);
    float4 a2 = *(const float4*)(pq + 2 * S + o);
    float4 a3 = *(const float4*)(pq + 3 * S + o);
    float4 a4 = *(const float4*)(pq + 4 * S + o);
    float4 a5 = *(const float4*)(pq + 5 * S + o);
    float4 a6 = *(const float4*)(pq + 6 * S + o);
    float4 a7 = *(const float4*)(pq + 7 * S + o);
    float4 r = make_float4(((a0.x + a1.x) + (a2.x + a3.x)) + ((a4.x + a5.x) + (a6.x + a7.x)),
                           ((a0.y + a1.y) + (a2.y + a3.y)) + ((a4.y + a5.y) + (a6.y + a7.y)),
                           ((a0.z + a1.z) + (a2.z + a3.z)) + ((a4.z + a5.z) + (a6.z + a7.z)),
                           ((a0.w + a1.w) + (a2.w + a3.w)) + ((a4.w + a5.w) + (a6.w + a7.w)));
    const int which = f >> 6;          // 0=q 1=sk 2=v
    const int h = f & 63;
    *(float4*)(qsv + (size_t)which * 131072 + (size_t)h * 2048 + i) = r;
}

// attn: block = (h, p), p=0..15 handles row-blocks rb1=p and rb2=31-p.
// Total j-work per block = (p+1)*64 + (32-p)*64 = 2112 (uniform!). 4 waves
// each take a 528-elem (16-aligned) slice of the concatenated [A|B] range.
// Scores bounded (|score| <~ 1.3 nats) -> no max subtraction.
__global__ __launch_bounds__(256) void attn_kernel(const float* __restrict__ qsv,
                                                   float* __restrict__ pn,
                                                   float* __restrict__ pd) {
    __shared__ float ssk[2048];
    __shared__ float svv[2048];
    const int t = threadIdx.x;
    const int h = blockIdx.x & 63;
    const int p = blockIdx.x >> 6;          // 0..15
    const int lane = t & 63;
    const int c = t >> 6;                   // j-slice 0..3

    const int Alen = (p + 1) * 64;          // rows rb1=p need j in [0, Alen)
    const int L    = (32 - p) * 64;         // rows rb2=31-p need j in [0, L); Alen <= L
    const float* skp = qsv + 131072 + (size_t)h * 2048;
    const float* vp  = qsv + 262144 + (size_t)h * 2048;

    for (int idx = t * 4; idx < L; idx += 1024) {
        *(float4*)&ssk[idx] = *(const float4*)(skp + idx);
        *(float4*)&svv[idx] = *(const float4*)(vp + idx);
    }
    __syncthreads();

    const int i1 = Alen - 64 + lane;        // row in block rb1
    const int i2 = L - 64 + lane;           // row in block rb2
    const float qv1 = qsv[(size_t)h * 2048 + i1];
    const float qv2 = qsv[(size_t)h * 2048 + i2];

    float dA[4] = {0.f, 0.f, 0.f, 0.f}, nA[4] = {0.f, 0.f, 0.f, 0.f};
    float dB[4] = {0.f, 0.f, 0.f, 0.f}, nB[4] = {0.f, 0.f, 0.f, 0.f};

    const int gs = c * 528, ge = gs + 528;

    // ---- part A: rows rb1=p, j-range [gs, min(ge,Alen)) ----
    if (gs < Alen) {
        const int a1 = (ge < Alen) ? ge : Alen;
        const int d1 = Alen - 64;           // diagonal block start
        const int be = (a1 < d1) ? a1 : d1;
        for (int j = gs; j < be; j += 16) {
#pragma unroll
            for (int u = 0; u < 4; ++u) {
                float4 s = *(const float4*)&ssk[j + 4 * u];
                float4 v = *(const float4*)&svv[j + 4 * u];
                float e0 = EXP2F(qv1 * s.x), e1 = EXP2F(qv1 * s.y);
                float e2 = EXP2F(qv1 * s.z), e3 = EXP2F(qv1 * s.w);
                dA[0] += e0; nA[0] = fmaf(e0, v.x, nA[0]);
                dA[1] += e1; nA[1] = fmaf(e1, v.y, nA[1]);
                dA[2] += e2; nA[2] = fmaf(e2, v.z, nA[2]);
                dA[3] += e3; nA[3] = fmaf(e3, v.w, nA[3]);
            }
        }
        const int ms = (gs > d1) ? gs : d1;
        for (int j = ms; j < a1; j += 16) {
#pragma unroll
            for (int u = 0; u < 4; ++u) {
                float4 s = *(const float4*)&ssk[j + 4 * u];
                float4 v = *(const float4*)&svv[j + 4 * u];
                const int jb = j + 4 * u;
                float e0 = (jb     <= i1) ? EXP2F(qv1 * s.x) : 0.f;
                float e1 = (jb + 1 <= i1) ? EXP2F(qv1 * s.y) : 0.f;
                float e2 = (jb + 2 <= i1) ? EXP2F(qv1 * s.z) : 0.f;
                float e3 = (jb + 3 <= i1) ? EXP2F(qv1 * s.w) : 0.f;
                dA[0] += e0; nA[0] = fmaf(e0, v.x, nA[0]);
                dA[1] += e1; nA[1] = fmaf(e1, v.y, nA[1]);
                dA[2] += e2; nA[2] = fmaf(e2, v.z, nA[2]);
                dA[3] += e3; nA[3] = fmaf(e3, v.w, nA[3]);
            }
        }
    }

    // ---- part B: rows rb2=31-p, j-range [max(gs,Alen)-Alen, ge-Alen) ----
    if (ge > Alen) {
        const int b0 = ((gs > Alen) ? gs : Alen) - Alen;
        const int b1 = ge - Alen;
        const int d2 = L - 64;
        const int be = (b1 < d2) ? b1 : d2;
        for (int j = b0; j < be; j += 16) {
#pragma unroll
            for (int u = 0; u < 4; ++u) {
                float4 s = *(const float4*)&ssk[j + 4 * u];
                float4 v = *(const float4*)&svv[j + 4 * u];
                float e0 = EXP2F(qv2 * s.x), e1 = EXP2F(qv2 * s.y);
                float e2 = EXP2F(qv2 * s.z), e3 = EXP2F(qv2 * s.w);
                dB[0] += e0; nB[0] = fmaf(e0, v.x, nB[0]);
                dB[1] += e1; nB[1] = fmaf(e1, v.y, nB[1]);
                dB[2] += e2; nB[2] = fmaf(e2, v.z, nB[2]);
                dB[3] += e3; nB[3] = fmaf(e3, v.w, nB[3]);
            }
        }
        const int ms = (b0 > d2) ? b0 : d2;
        for (int j = ms; j < b1; j += 16) {
#pragma unroll
            for (int u = 0; u < 4; ++u) {
                float4 s = *(const float4*)&ssk[j + 4 * u];
                float4 v = *(const float4*)&svv[j + 4 * u];
                const int jb = j + 4 * u;
                float e0 = (jb     <= i2) ? EXP2F(qv2 * s.x) : 0.f;
                float e1 = (jb + 1 <= i2) ? EXP2F(qv2 * s.y) : 0.f;
                float e2 = (jb + 2 <= i2) ? EXP2F(qv2 * s.z) : 0.f;
                float e3 = (jb + 3 <= i2) ? EXP2F(qv2 * s.w) : 0.f;
                dB[0] += e0; nB[0] = fmaf(e0, v.x, nB[0]);
                dB[1] += e1; nB[1] = fmaf(e1, v.y, nB[1]);
                dB[2] += e2; nB[2] = fmaf(e2, v.z, nB[2]);
                dB[3] += e3; nB[3] = fmaf(e3, v.w, nB[3]);
            }
        }
    }

    const size_t base = ((size_t)c * 64 + h) * 2048;
    pn[base + i1] = (nA[0] + nA[1]) + (nA[2] + nA[3]);
    pd[base + i1] = (dA[0] + dA[1]) + (dA[2] + dA[3]);
    pn[base + i2] = (nB[0] + nB[1]) + (nB[2] + nB[3]);
    pd[base + i2] = (dB[0] + dB[1]) + (dB[2] + dB[3]);
}

// proj: out[i][c] = sum_h a[i][h] * wOutT[h][c], a = (sum pn slots)/(sum pd slots).
// grid 2048 = 256 i-tiles(8 rows) x 8 c-tiles(128 cols); block 256.
__global__ __launch_bounds__(256) void proj_kernel(const float* __restrict__ pn,
                                                   const float* __restrict__ pd,
                                                   const float* __restrict__ wOutT,
                                                   float* __restrict__ out) {
    __shared__ float ast[64][8];
    const int t = threadIdx.x;
    const int i0 = (blockIdx.x >> 3) * 8;
    const int c0 = (blockIdx.x & 7) * 128;

    for (int s = t; s < 512; s += 256) {
        const int hh = s >> 3, ii = s & 7;
        const size_t o = (size_t)hh * 2048 + i0 + ii;
        float n = (pn[o] + pn[131072 + o]) + (pn[262144 + o] + pn[393216 + o]);
        float d = (pd[o] + pd[131072 + o]) + (pd[262144 + o] + pd[393216 + o]);
        ast[hh][ii] = n / d;
    }
    __syncthreads();

    const int rg = t >> 5;      // row 0..7
    const int cg = t & 31;      // col-quad 0..31
    const float* wp = wOutT + c0 + cg * 4;
    float a0 = 0.f, a1 = 0.f, a2 = 0.f, a3 = 0.f;
#pragma unroll 8
    for (int hc = 0; hc < 64; ++hc) {
        float4 w4 = *(const float4*)(wp + (size_t)hc * 1024);
        float a = ast[hc][rg];
        a0 = fmaf(a, w4.x, a0);
        a1 = fmaf(a, w4.y, a1);
        a2 = fmaf(a, w4.z, a2);
        a3 = fmaf(a, w4.w, a3);
    }
    *(float4*)(out + (size_t)(i0 + rg) * 1024 + c0 + cg * 4) = make_float4(a0, a1, a2, a3);
}

extern "C" void kernel_launch(void* const* d_in, const int* in_sizes, int n_in,
                              void* d_out, int out_size, void* d_ws, size_t ws_size,
                              hipStream_t stream) {
    const float* x     = (const float*)d_in[0];   // [1,2048,1024]
    const float* w_qkv = (const float*)d_in[1];   // [192,1024]
    const float* w_out = (const float*)d_in[2];   // [1024,64]
    float* out = (float*)d_out;                   // [1,2048,1024]

    float* ws    = (float*)d_ws;
    float* wT    = ws;                 // 196608
    float* wOutT = wT + 196608;        // 65536
    float* qsv   = wOutT + 65536;      // 3*64*2048 = 393216  (q | sk | v)
    float* scr   = qsv + 393216;       // scratch: pq[8*192*2048=3145728] OR pn|pd
    float* pq    = scr;                // alive: qkv_gemm -> qkv_reduce
    float* pn    = scr;                // alive: attn -> proj (aliases dead pq)
    float* pd    = scr + 524288;

    prep_kernel<<<dim3(1024), dim3(256), 0, stream>>>(w_qkv, w_out, wT, wOutT);
    qkv_gemm<<<dim3(768), dim3(256), 0, stream>>>(x, wT, pq);
    qkv_reduce<<<dim3(384), dim3(256), 0, stream>>>(pq, qsv);
    attn_kernel<<<dim3(1024), dim3(256), 0, stream>>>(qsv, pn, pd);
    proj_kernel<<<dim3(2048), dim3(256), 0, stream>>>(pn, pd, wOutT, out);
}

// Round 12
// 122.565 us; speedup vs baseline: 1.3553x; 1.0365x over previous
//
#include <hip/hip_runtime.h>

// CausalWanSelfAttention: DIM=1024, 64 heads of head-dim 1, N=2048.
// out[i,c] = sum_h w_out[c,h] * softmax_j<=i( q[i,h]*k[j,h]/8 ) . v[j,h]
//
// 5 kernels:
//   prep:       LDS-tiled transposes: wT[k][f] (k-rows of f in [64,128) pre-scaled
//               by log2e/8), wOutT[h][c]
//   qkv_gemm:   128x64 tiles, 8x4 micro, split-K=16 -> pq[16][192][2048] f-major
//   qkv_reduce: sum 16 partials -> qsv = q|sk|v [3][64][2048]
//   attn:       block=(h, pair{p,31-p}), 8 waves x 264-j slices, LDS-staged sk/v,
//               exp2 hot loop, cross-wave LDS reduce -> aws[h][i] (final a values)
//   proj:       out = a . wOutT  (16x128-col tiles)

#if __has_builtin(__builtin_amdgcn_exp2f)
#define EXP2F(x) __builtin_amdgcn_exp2f(x)
#else
#define EXP2F(x) exp2f(x)
#endif

#define LOG2E_DIV8 0.18033688011112042f  // log2(e)/8

// grid 64: b<48 -> 64x64 tile of wqkv[192][1024] -> wT[1024][192] (scaled rows);
//          b>=48 -> 64x64 tile of wout[1024][64] -> wOutT[64][1024]
__global__ __launch_bounds__(256) void prep_kernel(const float* __restrict__ wqkv,
                                                   const float* __restrict__ wout,
                                                   float* __restrict__ wT,
                                                   float* __restrict__ wOutT) {
    __shared__ float tile[64][65];
    const int t = threadIdx.x;
    const int b = blockIdx.x;
    const int r = t & 63;
    const int g = t >> 6;     // 0..3
    if (b < 48) {
        const int f0 = (b % 3) * 64;
        const int k0 = (b / 3) * 64;
        // read rows f0+r, cols k0+g*16..+15 (coalesced float4)
#pragma unroll
        for (int j = 0; j < 4; ++j) {
            float4 v = *(const float4*)(wqkv + (size_t)(f0 + r) * 1024 + k0 + g * 16 + j * 4);
            tile[r][g * 16 + j * 4 + 0] = v.x;
            tile[r][g * 16 + j * 4 + 1] = v.y;
            tile[r][g * 16 + j * 4 + 2] = v.z;
            tile[r][g * 16 + j * 4 + 3] = v.w;
        }
        __syncthreads();
        const float sc = (f0 == 64) ? LOG2E_DIV8 : 1.0f;  // k-features f in [64,128)
        // write wT[k][f0+r], k = k0+g*16+j (lanes vary f -> coalesced)
#pragma unroll
        for (int j = 0; j < 16; ++j) {
            const int k = k0 + g * 16 + j;
            wT[(size_t)k * 192 + f0 + r] = tile[r][g * 16 + j] * sc;
        }
    } else {
        const int c0 = (b - 48) * 64;
        // read rows c0+r, cols h = g*16..+15
#pragma unroll
        for (int j = 0; j < 4; ++j) {
            float4 v = *(const float4*)(wout + (size_t)(c0 + r) * 64 + g * 16 + j * 4);
            tile[r][g * 16 + j * 4 + 0] = v.x;
            tile[r][g * 16 + j * 4 + 1] = v.y;
            tile[r][g * 16 + j * 4 + 2] = v.z;
            tile[r][g * 16 + j * 4 + 3] = v.w;
        }
        __syncthreads();
        // write wOutT[h][c0+r], h = g*16+j (lanes vary c -> coalesced)
#pragma unroll
        for (int j = 0; j < 16; ++j) {
            const int h = g * 16 + j;
            wOutT[(size_t)h * 1024 + c0 + r] = tile[r][h];
        }
    }
}

// C[2048][192] = x[2048][1024] * wT[1024][192], split-K=16 (K=64 per block).
// grid 768 = 16 mtiles(128) * 3 ntiles(64) * 16 ksplit; block 256; micro 8x4.
__global__ __launch_bounds__(256) void qkv_gemm(const float* __restrict__ x,
                                                const float* __restrict__ wT,
                                                float* __restrict__ pq) {
    __shared__ float xsT[32][128];  // [k][row]
    __shared__ float wsld[32][64];  // [k][f]
    const int t = threadIdx.x;
    const int b = blockIdx.x;
    const int ks = b & 15;
    const int nt = (b >> 4) % 3;
    const int mt = b / 48;
    const int i0 = mt * 128;
    const int cb = nt * 64;
    const int k0 = ks * 64;

    const int xr = t & 127;   // x staging row
    const int xq = t >> 7;    // 0..1 -> 16 k each
    const int wf = t & 63;    // w staging f
    const int wq = t >> 6;    // 0..3 -> 8 k each
    const int tx = t & 15;
    const int ty = t >> 4;

    const float* xp = x + (size_t)(i0 + xr) * 1024 + k0 + xq * 16;
    const float* wp = wT + (size_t)(k0 + wq * 8) * 192 + cb + wf;

    // prefetch stage 0
    float4 xa0 = *(const float4*)(xp);
    float4 xa1 = *(const float4*)(xp + 4);
    float4 xa2 = *(const float4*)(xp + 8);
    float4 xa3 = *(const float4*)(xp + 12);
    float wr[8];
#pragma unroll
    for (int j = 0; j < 8; ++j) wr[j] = wp[(size_t)j * 192];

    float acc[8][4] = {};

    for (int s = 0; s < 2; ++s) {
        __syncthreads();
        {
            const int kb = xq * 16;
            xsT[kb + 0][xr] = xa0.x; xsT[kb + 1][xr] = xa0.y;
            xsT[kb + 2][xr] = xa0.z; xsT[kb + 3][xr] = xa0.w;
            xsT[kb + 4][xr] = xa1.x; xsT[kb + 5][xr] = xa1.y;
            xsT[kb + 6][xr] = xa1.z; xsT[kb + 7][xr] = xa1.w;
            xsT[kb + 8][xr] = xa2.x; xsT[kb + 9][xr] = xa2.y;
            xsT[kb + 10][xr] = xa2.z; xsT[kb + 11][xr] = xa2.w;
            xsT[kb + 12][xr] = xa3.x; xsT[kb + 13][xr] = xa3.y;
            xsT[kb + 14][xr] = xa3.z; xsT[kb + 15][xr] = xa3.w;
            const int kw = wq * 8;
#pragma unroll
            for (int j = 0; j < 8; ++j) wsld[kw + j][wf] = wr[j];
        }
        __syncthreads();
        if (s == 0) {
            xa0 = *(const float4*)(xp + 32);
            xa1 = *(const float4*)(xp + 36);
            xa2 = *(const float4*)(xp + 40);
            xa3 = *(const float4*)(xp + 44);
            const float* wp2 = wp + (size_t)32 * 192;
#pragma unroll
            for (int j = 0; j < 8; ++j) wr[j] = wp2[(size_t)j * 192];
        }
#pragma unroll
        for (int k = 0; k < 32; ++k) {
            float4 a0 = *(const float4*)&xsT[k][ty * 8];
            float4 a1 = *(const float4*)&xsT[k][ty * 8 + 4];
            float4 b4 = *(const float4*)&wsld[k][tx * 4];
#pragma unroll
            for (int cc = 0; cc < 4; ++cc) {
                const float bb = (cc == 0) ? b4.x : (cc == 1) ? b4.y : (cc == 2) ? b4.z : b4.w;
                acc[0][cc] = fmaf(a0.x, bb, acc[0][cc]);
                acc[1][cc] = fmaf(a0.y, bb, acc[1][cc]);
                acc[2][cc] = fmaf(a0.z, bb, acc[2][cc]);
                acc[3][cc] = fmaf(a0.w, bb, acc[3][cc]);
                acc[4][cc] = fmaf(a1.x, bb, acc[4][cc]);
                acc[5][cc] = fmaf(a1.y, bb, acc[5][cc]);
                acc[6][cc] = fmaf(a1.z, bb, acc[6][cc]);
                acc[7][cc] = fmaf(a1.w, bb, acc[7][cc]);
            }
        }
    }

    // coalesced f-major partial write: pq[ks][cb+tx*4+cc][i0 + ty*8 .. +7]
    float* pbase = pq + (size_t)ks * 192 * 2048 + (size_t)cb * 2048 + i0;
#pragma unroll
    for (int cc = 0; cc < 4; ++cc) {
        float* dst = pbase + (size_t)(tx * 4 + cc) * 2048 + ty * 8;
        *(float4*)(dst)     = make_float4(acc[0][cc], acc[1][cc], acc[2][cc], acc[3][cc]);
        *(float4*)(dst + 4) = make_float4(acc[4][cc], acc[5][cc], acc[6][cc], acc[7][cc]);
    }
}

// sum 16 partials -> qsv (q|sk|v head-major). Scale already folded into wT.
__global__ __launch_bounds__(256) void qkv_reduce(const float* __restrict__ pq,
                                                  float* __restrict__ qsv) {
    const int idx = blockIdx.x * 256 + threadIdx.x;   // 98304 threads
    const int f = idx >> 9;                           // 0..191
    const int i = (idx & 511) * 4;
    const size_t S = (size_t)192 * 2048;
    const size_t o = (size_t)f * 2048 + i;
    float sx = 0.f, sy = 0.f, sz = 0.f, sw = 0.f;
#pragma unroll
    for (int s = 0; s < 16; ++s) {
        float4 a = *(const float4*)(pq + (size_t)s * S + o);
        sx += a.x; sy += a.y; sz += a.z; sw += a.w;
    }
    const int which = f >> 6;          // 0=q 1=sk 2=v
    const int h = f & 63;
    *(float4*)(qsv + (size_t)which * 131072 + (size_t)h * 2048 + i) =
        make_float4(sx, sy, sz, sw);
}

// attn: block = (h, p), p=0..15 handles row-blocks rb1=p and rb2=31-p.
// Total j-work = (p+1)*64 + (32-p)*64 = 2112 (uniform). 8 waves x 264-j slices.
// Cross-wave LDS reduce + divide -> aws[h][i] directly.
// Scores bounded (|score| <~ 1.3 nats) -> no max subtraction.
__global__ __launch_bounds__(512) void attn_kernel(const float* __restrict__ qsv,
                                                   float* __restrict__ aws) {
    __shared__ float ssk[2048];
    __shared__ float svv[2048];
    __shared__ float red[8][64][5];   // [slice][lane][{nA,dA,nB,dB}] (+pad)
    const int t = threadIdx.x;
    const int h = blockIdx.x & 63;
    const int p = blockIdx.x >> 6;          // 0..15
    const int lane = t & 63;
    const int c = t >> 6;                   // j-slice 0..7

    const int Alen = (p + 1) * 64;          // rows rb1=p need j in [0, Alen)
    const int L    = (32 - p) * 64;         // rows rb2=31-p need j in [0, L); Alen <= L
    const float* skp = qsv + 131072 + (size_t)h * 2048;
    const float* vp  = qsv + 262144 + (size_t)h * 2048;

    for (int idx = t * 4; idx < L; idx += 2048) {
        *(float4*)&ssk[idx] = *(const float4*)(skp + idx);
        *(float4*)&svv[idx] = *(const float4*)(vp + idx);
    }
    __syncthreads();

    const int i1 = Alen - 64 + lane;        // row in block rb1
    const int i2 = L - 64 + lane;           // row in block rb2
    const float qv1 = qsv[(size_t)h * 2048 + i1];
    const float qv2 = qsv[(size_t)h * 2048 + i2];

    float dA[4] = {0.f, 0.f, 0.f, 0.f}, nA[4] = {0.f, 0.f, 0.f, 0.f};
    float dB[4] = {0.f, 0.f, 0.f, 0.f}, nB[4] = {0.f, 0.f, 0.f, 0.f};

    const int gs = c * 264, ge = gs + 264;  // 264 = 33*8, 8-aligned

    // ---- part A: rows rb1=p, j-range [gs, min(ge,Alen)) ----
    if (gs < Alen) {
        const int a1 = (ge < Alen) ? ge : Alen;
        const int d1 = Alen - 64;           // diagonal block start
        const int be = (a1 < d1) ? a1 : d1;
        for (int j = gs; j < be; j += 8) {
#pragma unroll
            for (int u = 0; u < 2; ++u) {
                float4 s = *(const float4*)&ssk[j + 4 * u];
                float4 v = *(const float4*)&svv[j + 4 * u];
                float e0 = EXP2F(qv1 * s.x), e1 = EXP2F(qv1 * s.y);
                float e2 = EXP2F(qv1 * s.z), e3 = EXP2F(qv1 * s.w);
                dA[0] += e0; nA[0] = fmaf(e0, v.x, nA[0]);
                dA[1] += e1; nA[1] = fmaf(e1, v.y, nA[1]);
                dA[2] += e2; nA[2] = fmaf(e2, v.z, nA[2]);
                dA[3] += e3; nA[3] = fmaf(e3, v.w, nA[3]);
            }
        }
        const int ms = (gs > d1) ? gs : d1;
        for (int j = ms; j < a1; j += 8) {
#pragma unroll
            for (int u = 0; u < 2; ++u) {
                float4 s = *(const float4*)&ssk[j + 4 * u];
                float4 v = *(const float4*)&svv[j + 4 * u];
                const int jb = j + 4 * u;
                float e0 = (jb     <= i1) ? EXP2F(qv1 * s.x) : 0.f;
                float e1 = (jb + 1 <= i1) ? EXP2F(qv1 * s.y) : 0.f;
                float e2 = (jb + 2 <= i1) ? EXP2F(qv1 * s.z) : 0.f;
                float e3 = (jb + 3 <= i1) ? EXP2F(qv1 * s.w) : 0.f;
                dA[0] += e0; nA[0] = fmaf(e0, v.x, nA[0]);
                dA[1] += e1; nA[1] = fmaf(e1, v.y, nA[1]);
                dA[2] += e2; nA[2] = fmaf(e2, v.z, nA[2]);
                dA[3] += e3; nA[3] = fmaf(e3, v.w, nA[3]);
            }
        }
    }

    // ---- part B: rows rb2=31-p, j-range [max(gs,Alen)-Alen, ge-Alen) ----
    if (ge > Alen) {
        const int b0 = ((gs > Alen) ? gs : Alen) - Alen;
        const int b1 = ge - Alen;
        const int d2 = L - 64;
        const int be = (b1 < d2) ? b1 : d2;
        for (int j = b0; j < be; j += 8) {
#pragma unroll
            for (int u = 0; u < 2; ++u) {
                float4 s = *(const float4*)&ssk[j + 4 * u];
                float4 v = *(const float4*)&svv[j + 4 * u];
                float e0 = EXP2F(qv2 * s.x), e1 = EXP2F(qv2 * s.y);
                float e2 = EXP2F(qv2 * s.z), e3 = EXP2F(qv2 * s.w);
                dB[0] += e0; nB[0] = fmaf(e0, v.x, nB[0]);
                dB[1] += e1; nB[1] = fmaf(e1, v.y, nB[1]);
                dB[2] += e2; nB[2] = fmaf(e2, v.z, nB[2]);
                dB[3] += e3; nB[3] = fmaf(e3, v.w, nB[3]);
            }
        }
        const int ms = (b0 > d2) ? b0 : d2;
        for (int j = ms; j < b1; j += 8) {
#pragma unroll
            for (int u = 0; u < 2; ++u) {
                float4 s = *(const float4*)&ssk[j + 4 * u];
                float4 v = *(const float4*)&svv[j + 4 * u];
                const int jb = j + 4 * u;
                float e0 = (jb     <= i2) ? EXP2F(qv2 * s.x) : 0.f;
                float e1 = (jb + 1 <= i2) ? EXP2F(qv2 * s.y) : 0.f;
                float e2 = (jb + 2 <= i2) ? EXP2F(qv2 * s.z) : 0.f;
                float e3 = (jb + 3 <= i2) ? EXP2F(qv2 * s.w) : 0.f;
                dB[0] += e0; nB[0] = fmaf(e0, v.x, nB[0]);
                dB[1] += e1; nB[1] = fmaf(e1, v.y, nB[1]);
                dB[2] += e2; nB[2] = fmaf(e2, v.z, nB[2]);
                dB[3] += e3; nB[3] = fmaf(e3, v.w, nB[3]);
            }
        }
    }

    red[c][lane][0] = (nA[0] + nA[1]) + (nA[2] + nA[3]);
    red[c][lane][1] = (dA[0] + dA[1]) + (dA[2] + dA[3]);
    red[c][lane][2] = (nB[0] + nB[1]) + (nB[2] + nB[3]);
    red[c][lane][3] = (dB[0] + dB[1]) + (dB[2] + dB[3]);
    __syncthreads();

    if (t < 64) {
        float n = 0.f, d = 0.f;
#pragma unroll
        for (int s = 0; s < 8; ++s) { n += red[s][t][0]; d += red[s][t][1]; }
        aws[(size_t)h * 2048 + (Alen - 64 + t)] = n / d;
    } else if (t < 128) {
        const int l = t - 64;
        float n = 0.f, d = 0.f;
#pragma unroll
        for (int s = 0; s < 8; ++s) { n += red[s][l][2]; d += red[s][l][3]; }
        aws[(size_t)h * 2048 + (L - 64 + l)] = n / d;
    }
}

// proj: out[i][c] = sum_h aws[h][i] * wOutT[h][c].
// grid 2048 = 256 i-tiles(8 rows) x 8 c-tiles(128 cols); block 256.
__global__ __launch_bounds__(256) void proj_kernel(const float* __restrict__ aws,
                                                   const float* __restrict__ wOutT,
                                                   float* __restrict__ out) {
    __shared__ float ast[64][8];
    const int t = threadIdx.x;
    const int i0 = (blockIdx.x >> 3) * 8;
    const int c0 = (blockIdx.x & 7) * 128;

    for (int s = t; s < 512; s += 256) {
        const int hh = s >> 3, ii = s & 7;
        ast[hh][ii] = aws[(size_t)hh * 2048 + i0 + ii];
    }
    __syncthreads();

    const int rg = t >> 5;      // row 0..7
    const int cg = t & 31;      // col-quad 0..31
    const float* wp = wOutT + c0 + cg * 4;
    float a0 = 0.f, a1 = 0.f, a2 = 0.f, a3 = 0.f;
#pragma unroll 8
    for (int hc = 0; hc < 64; ++hc) {
        float4 w4 = *(const float4*)(wp + (size_t)hc * 1024);
        float a = ast[hc][rg];
        a0 = fmaf(a, w4.x, a0);
        a1 = fmaf(a, w4.y, a1);
        a2 = fmaf(a, w4.z, a2);
        a3 = fmaf(a, w4.w, a3);
    }
    *(float4*)(out + (size_t)(i0 + rg) * 1024 + c0 + cg * 4) = make_float4(a0, a1, a2, a3);
}

extern "C" void kernel_launch(void* const* d_in, const int* in_sizes, int n_in,
                              void* d_out, int out_size, void* d_ws, size_t ws_size,
                              hipStream_t stream) {
    const float* x     = (const float*)d_in[0];   // [1,2048,1024]
    const float* w_qkv = (const float*)d_in[1];   // [192,1024]
    const float* w_out = (const float*)d_in[2];   // [1024,64]
    float* out = (float*)d_out;                   // [1,2048,1024]

    float* ws    = (float*)d_ws;
    float* wT    = ws;                 // 196608
    float* wOutT = wT + 196608;        // 65536
    float* qsv   = wOutT + 65536;      // 3*64*2048 = 393216  (q | sk | v)
    float* aws   = qsv + 393216;       // 131072
    float* pq    = aws + 131072;       // 16*192*2048 = 6291456

    prep_kernel<<<dim3(64), dim3(256), 0, stream>>>(w_qkv, w_out, wT, wOutT);
    qkv_gemm<<<dim3(768), dim3(256), 0, stream>>>(x, wT, pq);
    qkv_reduce<<<dim3(384), dim3(256), 0, stream>>>(pq, qsv);
    attn_kernel<<<dim3(1024), dim3(512), 0, stream>>>(qsv, aws);
    proj_kernel<<<dim3(2048), dim3(256), 0, stream>>>(aws, wOutT, out);
}